// Round 1
// baseline (1222.640 us; speedup 1.0000x reference)
//
#include <hip/hip_runtime.h>
#include <math.h>

namespace {

constexpr int B = 4, N = 1024, D = 512, H = 8, DHd = 64, L = 6, DFFd = 2048;
constexpr int M = B * N;           // 4096
constexpr int QKVS = 3 * D;        // 1536, qkv row stride
constexpr float NEG = -1000000000.0f;
constexpr float R2c = 100.0f;

typedef __attribute__((ext_vector_type(8))) short bf16x8;
typedef __attribute__((ext_vector_type(4))) float f32x4;
typedef __attribute__((ext_vector_type(16))) float f32x16;

__device__ __forceinline__ short f2bf(float f) {
  union { float f; unsigned u; } c; c.f = f;
  unsigned r = (c.u + 0x7fffu + ((c.u >> 16) & 1u)) >> 16;
  return (short)r;
}

__device__ __forceinline__ float gelu_f(float x) {
  return 0.5f * x * (1.0f + erff(x * 0.70710678118654752f));
}

// ---------------- bias: (B,N,N) additive mask ----------------
__global__ __launch_bounds__(256) void bias_kernel(
    const float* __restrict__ xy, const int* __restrict__ alive,
    const int* __restrict__ species, float* __restrict__ bias)
{
  int j = blockIdx.x * 256 + threadIdx.x;
  int i = blockIdx.y;
  int b = blockIdx.z;
  float xi = xy[((size_t)b * N + i) * 2 + 0];
  float yi = xy[((size_t)b * N + i) * 2 + 1];
  float xj = xy[((size_t)b * N + j) * 2 + 0];
  float yj = xy[((size_t)b * N + j) * 2 + 1];
  float dx = xi - xj, dy = yi - yj;
  float d2 = dx * dx + dy * dy;
  float bv = 0.0f;
  if (alive[b * N + j] == 0) bv += NEG;
  if (d2 > R2c) bv += NEG;
  int si = species[b * N + i], sj = species[b * N + j];
  bool ia = si < 2, ip = si == 2, ja = sj < 2, jp = sj == 2;
  if ((ia && jp) || (ip && ja)) bv += NEG;
  bias[((size_t)b * N + i) * N + j] = bv;
}

// ---------------- weight prep: fp32 (K x Nc) -> bf16 transposed (Nc x K) ----------------
__global__ __launch_bounds__(256) void wprep_kernel(
    const float* __restrict__ src, short* __restrict__ dst,
    int K, int Nc, size_t srcLS, size_t dstLS)
{
  __shared__ float t[32][33];
  int k0 = blockIdx.x * 32, n0 = blockIdx.y * 32;
  src += (size_t)blockIdx.z * srcLS;
  dst += (size_t)blockIdx.z * dstLS;
  int r = threadIdx.x >> 5, c = threadIdx.x & 31;  // r: 0..7
#pragma unroll
  for (int i = 0; i < 4; ++i)
    t[r + i * 8][c] = src[(size_t)(k0 + r + i * 8) * Nc + n0 + c];
  __syncthreads();
#pragma unroll
  for (int i = 0; i < 4; ++i)
    dst[(size_t)(n0 + r + i * 8) * K + k0 + c] = f2bf(t[c][r + i * 8]);
}

// ---------------- LayerNorm: one wave per row of 512; bf16 or fp32 out ----------------
__global__ __launch_bounds__(64) void ln_kernel(
    const float* __restrict__ x, const float* __restrict__ g,
    const float* __restrict__ be, float* __restrict__ outf,
    short* __restrict__ outb)
{
  int row = blockIdx.x;
  int tid = threadIdx.x;
  const float* xr = x + (size_t)row * D;
  float v[8];
  float sum = 0.f;
#pragma unroll
  for (int i = 0; i < 8; ++i) { v[i] = xr[tid + i * 64]; sum += v[i]; }
#pragma unroll
  for (int off = 32; off > 0; off >>= 1) sum += __shfl_down(sum, off);
  sum = __shfl(sum, 0);
  float mean = sum * (1.0f / D);
  float vs = 0.f;
#pragma unroll
  for (int i = 0; i < 8; ++i) { float d = v[i] - mean; vs += d * d; }
#pragma unroll
  for (int off = 32; off > 0; off >>= 1) vs += __shfl_down(vs, off);
  vs = __shfl(vs, 0);
  float rstd = rsqrtf(vs * (1.0f / D) + 1e-5f);
#pragma unroll
  for (int i = 0; i < 8; ++i) {
    int c = tid + i * 64;
    float o = (v[i] - mean) * rstd * g[c] + be[c];
    if (outb) outb[(size_t)row * D + c] = f2bf(o);
    else      outf[(size_t)row * D + c] = o;
  }
}

// ---------------- 128x128 bf16 MFMA GEMM (m97-style 2-phase, global_load_lds) ----
// Block = 128x128 C-tile, 4 waves in 2x2; each wave owns a 64x64 quadrant
// (2x2 tiles of mfma_f32_32x32x16_bf16), so NO cross-wave reduction is needed.
// BK=32 double-buffered LDS (32 KB total); staging via global_load_lds width-16,
// each wave stages a 32-row stripe of A and of Bt (4 instrs/wave/K-step).
// vmcnt(4) keeps the next tile's 4 loads in flight across the barrier.
// blockIdx.z = split-K slice (nkz=1 or 2). With nkz=2, mode-1 epilogue uses
// atomicAdd into Cf (residual accumulate); bias bvec added by kz==0 only.
// mode 0: Cb = bf16(acc); mode 1: Cf += acc (+bvec); mode 2: Cb = bf16(gelu(acc+bvec)).
__global__ __launch_bounds__(256, 3) void gemm128_kernel(
    const short* __restrict__ A, const short* __restrict__ Bt,
    const float* __restrict__ bvec, float* __restrict__ Cf,
    short* __restrict__ Cb, int K, int Nc, int mode, int nkz)
{
  __shared__ __align__(16) short As[2][4096];   // [buf][128 rows x 32 k] row-major
  __shared__ __align__(16) short Bs[2][4096];
  const int bm = blockIdx.y * 128, bn = blockIdx.x * 128;
  const int kz = blockIdx.z;
  const int t = threadIdx.x, wave = t >> 6, lane = t & 63;
  const int wr = wave >> 1, wc = wave & 1;
  const int l32 = lane & 31, half = lane >> 5;
  const int Kz = K / nkz;
  const int kw0 = kz * Kz;
  const int nch = Kz >> 5;          // K-steps of 32

  // staging: wave w covers rows [w*32, w*32+32): instr i -> rows w*32+i*16+(lane>>2)
  const short* Ab = A  + (size_t)(bm + wave * 32 + (lane >> 2)) * K + kw0 + (lane & 3) * 8;
  const short* Bb = Bt + (size_t)(bn + wave * 32 + (lane >> 2)) * K + kw0 + (lane & 3) * 8;
  char* Abase = (char*)&As[0][0] + wave * 2048;
  char* Bbase = (char*)&Bs[0][0] + wave * 2048;

  auto issue = [&](int p, int kc) {
#pragma unroll
    for (int i = 0; i < 2; ++i)
      __builtin_amdgcn_global_load_lds(
          (const __attribute__((address_space(1))) void*)(Ab + (size_t)i * 16 * K + kc),
          (__attribute__((address_space(3))) void*)(Abase + p * 8192 + i * 1024), 16, 0, 0);
#pragma unroll
    for (int i = 0; i < 2; ++i)
      __builtin_amdgcn_global_load_lds(
          (const __attribute__((address_space(1))) void*)(Bb + (size_t)i * 16 * K + kc),
          (__attribute__((address_space(3))) void*)(Bbase + p * 8192 + i * 1024), 16, 0, 0);
  };

  f32x16 acc[2][2];
#pragma unroll
  for (int i = 0; i < 2; ++i)
#pragma unroll
    for (int j = 0; j < 2; ++j)
#pragma unroll
      for (int r = 0; r < 16; ++r) acc[i][j][r] = 0.f;

  issue(0, 0);
  for (int c = 0; c < nch; ++c) {
    const int p = c & 1;
    if (c + 1 < nch) {
      issue(p ^ 1, (c + 1) * 32);
      asm volatile("s_waitcnt vmcnt(%0)" :: "i"(4) : "memory");
    } else {
      asm volatile("s_waitcnt vmcnt(0)" ::: "memory");
    }
    __syncthreads();
    const short* Ap = &As[p][0];
    const short* Bp = &Bs[p][0];
#pragma unroll
    for (int ks = 0; ks < 2; ++ks) {
      bf16x8 a0 = *(const bf16x8*)&Ap[(wr * 64 + l32) * 32 + ks * 16 + half * 8];
      bf16x8 a1 = *(const bf16x8*)&Ap[(wr * 64 + 32 + l32) * 32 + ks * 16 + half * 8];
      bf16x8 b0 = *(const bf16x8*)&Bp[(wc * 64 + l32) * 32 + ks * 16 + half * 8];
      bf16x8 b1 = *(const bf16x8*)&Bp[(wc * 64 + 32 + l32) * 32 + ks * 16 + half * 8];
      acc[0][0] = __builtin_amdgcn_mfma_f32_32x32x16_bf16(a0, b0, acc[0][0], 0, 0, 0);
      acc[0][1] = __builtin_amdgcn_mfma_f32_32x32x16_bf16(a0, b1, acc[0][1], 0, 0, 0);
      acc[1][0] = __builtin_amdgcn_mfma_f32_32x32x16_bf16(a1, b0, acc[1][0], 0, 0, 0);
      acc[1][1] = __builtin_amdgcn_mfma_f32_32x32x16_bf16(a1, b1, acc[1][1], 0, 0, 0);
    }
    if (c + 1 < nch) __syncthreads();
  }

  // ---- epilogue: each wave writes its own 64x64 quadrant (no LDS, no barrier) ----
  float bv0 = 0.f, bv1 = 0.f;
  if (mode == 2 || (mode == 1 && kz == 0)) {
    bv0 = bvec[bn + wc * 64 + l32];
    bv1 = bvec[bn + wc * 64 + 32 + l32];
  }
#pragma unroll
  for (int ti = 0; ti < 2; ++ti)
#pragma unroll
    for (int tj = 0; tj < 2; ++tj) {
      const float vb = tj ? bv1 : bv0;
#pragma unroll
      for (int r = 0; r < 16; ++r) {
        const int row = bm + wr * 64 + ti * 32 + (r & 3) + 8 * (r >> 2) + 4 * half;
        const int col = bn + wc * 64 + tj * 32 + l32;
        const size_t idx = (size_t)row * Nc + col;
        const float v = acc[ti][tj][r];
        if (mode == 0) {
          Cb[idx] = f2bf(v);
        } else if (mode == 1) {
          if (nkz == 1) Cf[idx] += v + vb;
          else          atomicAdd(&Cf[idx], v + vb);
        } else {
          Cb[idx] = f2bf(gelu_f(v + vb));
        }
      }
    }
}

// ---------------- MFMA flash attention v2: S^T orientation, 1 barrier/ktile ----------------
__global__ __launch_bounds__(256) void attn_mfma_kernel(
    const short* __restrict__ qkv, const float* __restrict__ bias,
    short* __restrict__ o)
{
  constexpr int LDR = 72;
  __shared__ __align__(16) short Qs[64 * LDR];
  __shared__ __align__(16) short Ks[2][64 * LDR];
  __shared__ __align__(16) short Vt[2][64 * LDR];
  __shared__ __align__(16) short Ps[4 * 16 * LDR];

  const int q0 = blockIdx.x * 64;
  const int hh = blockIdx.y;
  const int b  = blockIdx.z;
  const int t  = threadIdx.x;
  const int wave = t >> 6;
  const int lane = t & 63;
  const int quad = lane >> 4;
  const int ln16 = lane & 15;
  const int srow = t >> 2, sseg = t & 3;

  {
    const short* qb = qkv + (size_t)(b * N + q0 + srow) * QKVS + hh * 64 + sseg * 16;
    *(bf16x8*)&Qs[srow * LDR + sseg * 16] = *(const bf16x8*)qb;
    *(bf16x8*)&Qs[srow * LDR + sseg * 16 + 8] = *(const bf16x8*)(qb + 8);
  }
  __syncthreads();

  const int qrow = wave * 16 + ln16;
  const bf16x8 qf0 = *(const bf16x8*)&Qs[qrow * LDR + quad * 8];
  const bf16x8 qf1 = *(const bf16x8*)&Qs[qrow * LDR + 32 + quad * 8];

  float m_run = -1e30f, l_run = 0.f;
  f32x4 Oacc[4];
#pragma unroll
  for (int dt = 0; dt < 4; ++dt) Oacc[dt] = (f32x4){0.f, 0.f, 0.f, 0.f};

  short* Psw = Ps + wave * 16 * LDR;
  const float* brow = bias + (size_t)(b * N + q0 + wave * 16 + ln16) * N;
  const short* kb0 = qkv + (size_t)b * N * QKVS + 512 + hh * 64 + sseg * 16;
  const short* vb0 = qkv + (size_t)b * N * QKVS + 1024 + hh * 64 + sseg * 16;

  bf16x8 k0r = *(const bf16x8*)(kb0 + (size_t)srow * QKVS);
  bf16x8 k1r = *(const bf16x8*)(kb0 + (size_t)srow * QKVS + 8);
  bf16x8 v0r = *(const bf16x8*)(vb0 + (size_t)srow * QKVS);
  bf16x8 v1r = *(const bf16x8*)(vb0 + (size_t)srow * QKVS + 8);
  float4 b4[4];
#pragma unroll
  for (int ks = 0; ks < 4; ++ks)
    b4[ks] = *(const float4*)&brow[ks * 16 + quad * 4];

  for (int kt = 0; kt < 16; ++kt) {
    const int p = kt & 1;
    *(bf16x8*)&Ks[p][srow * LDR + sseg * 16] = k0r;
    *(bf16x8*)&Ks[p][srow * LDR + sseg * 16 + 8] = k1r;
#pragma unroll
    for (int e = 0; e < 8; ++e) {
      Vt[p][(sseg * 16 + e) * LDR + srow] = v0r[e];
      Vt[p][(sseg * 16 + 8 + e) * LDR + srow] = v1r[e];
    }
    const int k0n = (kt + 1 < 16) ? (kt + 1) * 64 : 0;
    bf16x8 nk0 = *(const bf16x8*)(kb0 + (size_t)(k0n + srow) * QKVS);
    bf16x8 nk1 = *(const bf16x8*)(kb0 + (size_t)(k0n + srow) * QKVS + 8);
    bf16x8 nv0 = *(const bf16x8*)(vb0 + (size_t)(k0n + srow) * QKVS);
    bf16x8 nv1 = *(const bf16x8*)(vb0 + (size_t)(k0n + srow) * QKVS + 8);
    float4 bcur[4] = {b4[0], b4[1], b4[2], b4[3]};
#pragma unroll
    for (int ks = 0; ks < 4; ++ks)
      b4[ks] = *(const float4*)&brow[k0n + ks * 16 + quad * 4];
    asm volatile("s_waitcnt lgkmcnt(0)\n\ts_barrier" ::: "memory");

    float sv[4][4];
#pragma unroll
    for (int ks = 0; ks < 4; ++ks) {
      bf16x8 a0 = *(const bf16x8*)&Ks[p][(ks * 16 + ln16) * LDR + quad * 8];
      bf16x8 a1 = *(const bf16x8*)&Ks[p][(ks * 16 + ln16) * LDR + 32 + quad * 8];
      f32x4 z = (f32x4){0.f, 0.f, 0.f, 0.f};
      z = __builtin_amdgcn_mfma_f32_16x16x32_bf16(a0, qf0, z, 0, 0, 0);
      z = __builtin_amdgcn_mfma_f32_16x16x32_bf16(a1, qf1, z, 0, 0, 0);
#pragma unroll
      for (int r = 0; r < 4; ++r)
        sv[ks][r] = z[r] * 0.125f + (&bcur[ks].x)[r];
    }

    float mt = sv[0][0];
#pragma unroll
    for (int ks = 0; ks < 4; ++ks)
#pragma unroll
      for (int r = 0; r < 4; ++r) mt = fmaxf(mt, sv[ks][r]);
    mt = fmaxf(mt, __shfl_xor(mt, 16));
    mt = fmaxf(mt, __shfl_xor(mt, 32));
    const float m_new = fmaxf(m_run, mt);
    const float alpha = __expf(m_run - m_new);
    m_run = m_new;
    float rs = 0.f;
    float pv[4][4];
#pragma unroll
    for (int ks = 0; ks < 4; ++ks)
#pragma unroll
      for (int r = 0; r < 4; ++r) {
        float e = __expf(sv[ks][r] - m_new);
        pv[ks][r] = e;
        rs += e;
      }
    rs += __shfl_xor(rs, 16);
    rs += __shfl_xor(rs, 32);
    l_run = l_run * alpha + rs;
    float af[4];
#pragma unroll
    for (int r = 0; r < 4; ++r) af[r] = __shfl(alpha, quad * 4 + r);
#pragma unroll
    for (int dt = 0; dt < 4; ++dt)
#pragma unroll
      for (int r = 0; r < 4; ++r) Oacc[dt][r] *= af[r];

#pragma unroll
    for (int ks = 0; ks < 4; ++ks) {
      short4 pk = {f2bf(pv[ks][0]), f2bf(pv[ks][1]), f2bf(pv[ks][2]), f2bf(pv[ks][3])};
      *(short4*)&Psw[ln16 * LDR + ks * 16 + quad * 4] = pk;
    }

    bf16x8 ap0 = *(const bf16x8*)&Psw[ln16 * LDR + quad * 8];
    bf16x8 ap1 = *(const bf16x8*)&Psw[ln16 * LDR + 32 + quad * 8];
#pragma unroll
    for (int dt = 0; dt < 4; ++dt) {
      bf16x8 bv0 = *(const bf16x8*)&Vt[p][(dt * 16 + ln16) * LDR + quad * 8];
      bf16x8 bv1 = *(const bf16x8*)&Vt[p][(dt * 16 + ln16) * LDR + 32 + quad * 8];
      Oacc[dt] = __builtin_amdgcn_mfma_f32_16x16x32_bf16(ap0, bv0, Oacc[dt], 0, 0, 0);
      Oacc[dt] = __builtin_amdgcn_mfma_f32_16x16x32_bf16(ap1, bv1, Oacc[dt], 0, 0, 0);
    }

    k0r = nk0; k1r = nk1; v0r = nv0; v1r = nv1;
  }

  const float linv = 1.0f / l_run;
  float iv[4];
#pragma unroll
  for (int r = 0; r < 4; ++r) iv[r] = __shfl(linv, quad * 4 + r);
#pragma unroll
  for (int dt = 0; dt < 4; ++dt) {
#pragma unroll
    for (int r = 0; r < 4; ++r) {
      int row = q0 + wave * 16 + quad * 4 + r;
      o[(size_t)(b * N + row) * D + hh * 64 + dt * 16 + ln16] =
          f2bf(Oacc[dt][r] * iv[r]);
    }
  }
}

}  // namespace

extern "C" void kernel_launch(void* const* d_in, const int* in_sizes, int n_in,
                              void* d_out, int out_size, void* d_ws, size_t ws_size,
                              hipStream_t stream)
{
  const float* tokens  = (const float*)d_in[0];
  const float* xy      = (const float*)d_in[1];
  const float* Wq      = (const float*)d_in[2];
  const float* Wk      = (const float*)d_in[3];
  const float* Wv      = (const float*)d_in[4];
  const float* Wo      = (const float*)d_in[5];
  const float* bo      = (const float*)d_in[6];
  const float* W1      = (const float*)d_in[7];
  const float* b1      = (const float*)d_in[8];
  const float* W2      = (const float*)d_in[9];
  const float* b2      = (const float*)d_in[10];
  const float* g1      = (const float*)d_in[11];
  const float* be1     = (const float*)d_in[12];
  const float* g2      = (const float*)d_in[13];
  const float* be2     = (const float*)d_in[14];
  const float* gf      = (const float*)d_in[15];
  const float* bf      = (const float*)d_in[16];
  const int*   alive   = (const int*)d_in[17];
  const int*   species = (const int*)d_in[18];

  char* p = (char*)d_ws;
  float* bias = (float*)p; p += (size_t)B * N * N * 4;       // 16.78 MB
  float* x    = (float*)p; p += (size_t)M * D * 4;           // 8.39 MB
  short* h    = (short*)p; p += (size_t)M * D * 2;           // 4.19 MB
  short* qkv  = (short*)p; p += (size_t)M * DFFd * 2;        // 16.78 MB (ff aliases qkv)
  short* ff   = qkv;
  short* Wqkvt = (short*)p; p += (size_t)L * QKVS * D * 2;   // 9.44 MB
  short* Wot   = (short*)p; p += (size_t)L * D * D * 2;      // 3.15 MB
  short* W1t   = (short*)p; p += (size_t)L * DFFd * D * 2;   // 12.58 MB
  short* W2t   = (short*)p; p += (size_t)L * D * DFFd * 2;   // 12.58 MB

  hipMemcpyAsync(x, tokens, sizeof(float) * (size_t)M * D,
                 hipMemcpyDeviceToDevice, stream);
  bias_kernel<<<dim3(N / 256, N, B), 256, 0, stream>>>(xy, alive, species, bias);

  wprep_kernel<<<dim3(16, 16, L), 256, 0, stream>>>(
      Wq, Wqkvt + (size_t)0 * D * D, D, D, (size_t)D * D, (size_t)QKVS * D);
  wprep_kernel<<<dim3(16, 16, L), 256, 0, stream>>>(
      Wk, Wqkvt + (size_t)1 * D * D, D, D, (size_t)D * D, (size_t)QKVS * D);
  wprep_kernel<<<dim3(16, 16, L), 256, 0, stream>>>(
      Wv, Wqkvt + (size_t)2 * D * D, D, D, (size_t)D * D, (size_t)QKVS * D);
  wprep_kernel<<<dim3(16, 16, L), 256, 0, stream>>>(
      Wo, Wot, D, D, (size_t)D * D, (size_t)D * D);
  wprep_kernel<<<dim3(16, 64, L), 256, 0, stream>>>(
      W1, W1t, D, DFFd, (size_t)D * DFFd, (size_t)DFFd * D);
  wprep_kernel<<<dim3(64, 16, L), 256, 0, stream>>>(
      W2, W2t, DFFd, D, (size_t)DFFd * D, (size_t)D * DFFd);

  for (int l = 0; l < L; ++l) {
    ln_kernel<<<M, 64, 0, stream>>>(x, g1 + l * D, be1 + l * D, nullptr, h);
    // QKV: M=4096 x N=1536 x K=512
    gemm128_kernel<<<dim3(QKVS / 128, M / 128, 1), 256, 0, stream>>>(
        h, Wqkvt + (size_t)l * QKVS * D, nullptr, nullptr, qkv, D, QKVS, 0, 1);
    attn_mfma_kernel<<<dim3(N / 64, H, B), 256, 0, stream>>>(qkv, bias, h);
    // Wo: 4096 x 512 x 512, split-K=2 -> 256 blocks, atomic residual add
    gemm128_kernel<<<dim3(D / 128, M / 128, 2), 256, 0, stream>>>(
        h, Wot + (size_t)l * D * D, bo + l * D, x, nullptr, D, D, 1, 2);
    ln_kernel<<<M, 64, 0, stream>>>(x, g2 + l * D, be2 + l * D, nullptr, h);
    // W1: 4096 x 2048 x 512, gelu epilogue
    gemm128_kernel<<<dim3(DFFd / 128, M / 128, 1), 256, 0, stream>>>(
        h, W1t + (size_t)l * DFFd * D, b1 + l * DFFd, nullptr, ff, D, DFFd, 2, 1);
    // W2: 4096 x 512 x 2048, split-K=2 -> 256 blocks, atomic residual add
    gemm128_kernel<<<dim3(D / 128, M / 128, 2), 256, 0, stream>>>(
        ff, W2t + (size_t)l * D * DFFd, b2 + l * D, x, nullptr, DFFd, D, 1, 2);
  }
  ln_kernel<<<M, 64, 0, stream>>>(x, gf, bf, (float*)d_out, nullptr);
}

// Round 3
// 1157.026 us; speedup vs baseline: 1.0567x; 1.0567x over previous
//
#include <hip/hip_runtime.h>
#include <math.h>

namespace {

constexpr int B = 4, N = 1024, D = 512, H = 8, DHd = 64, L = 6, DFFd = 2048;
constexpr int M = B * N;           // 4096
constexpr int QKVS = 3 * D;        // 1536, qkv row stride
constexpr float NEG = -1000000000.0f;
constexpr float R2c = 100.0f;

typedef __attribute__((ext_vector_type(8))) short bf16x8;
typedef __attribute__((ext_vector_type(4))) float f32x4;
typedef __attribute__((ext_vector_type(16))) float f32x16;

__device__ __forceinline__ short f2bf(float f) {
  union { float f; unsigned u; } c; c.f = f;
  unsigned r = (c.u + 0x7fffu + ((c.u >> 16) & 1u)) >> 16;
  return (short)r;
}

__device__ __forceinline__ float gelu_f(float x) {
  return 0.5f * x * (1.0f + erff(x * 0.70710678118654752f));
}

// ---------------- bias: (B,N,N) additive mask ----------------
__global__ __launch_bounds__(256) void bias_kernel(
    const float* __restrict__ xy, const int* __restrict__ alive,
    const int* __restrict__ species, float* __restrict__ bias)
{
  int j = blockIdx.x * 256 + threadIdx.x;
  int i = blockIdx.y;
  int b = blockIdx.z;
  float xi = xy[((size_t)b * N + i) * 2 + 0];
  float yi = xy[((size_t)b * N + i) * 2 + 1];
  float xj = xy[((size_t)b * N + j) * 2 + 0];
  float yj = xy[((size_t)b * N + j) * 2 + 1];
  float dx = xi - xj, dy = yi - yj;
  float d2 = dx * dx + dy * dy;
  float bv = 0.0f;
  if (alive[b * N + j] == 0) bv += NEG;
  if (d2 > R2c) bv += NEG;
  int si = species[b * N + i], sj = species[b * N + j];
  bool ia = si < 2, ip = si == 2, ja = sj < 2, jp = sj == 2;
  if ((ia && jp) || (ip && ja)) bv += NEG;
  bias[((size_t)b * N + i) * N + j] = bv;
}

// ---------------- weight prep: fp32 (K x Nc) -> bf16 transposed (Nc x K) ----------------
__global__ __launch_bounds__(256) void wprep_kernel(
    const float* __restrict__ src, short* __restrict__ dst,
    int K, int Nc, size_t srcLS, size_t dstLS)
{
  __shared__ float t[32][33];
  int k0 = blockIdx.x * 32, n0 = blockIdx.y * 32;
  src += (size_t)blockIdx.z * srcLS;
  dst += (size_t)blockIdx.z * dstLS;
  int r = threadIdx.x >> 5, c = threadIdx.x & 31;  // r: 0..7
#pragma unroll
  for (int i = 0; i < 4; ++i)
    t[r + i * 8][c] = src[(size_t)(k0 + r + i * 8) * Nc + n0 + c];
  __syncthreads();
#pragma unroll
  for (int i = 0; i < 4; ++i)
    dst[(size_t)(n0 + r + i * 8) * K + k0 + c] = f2bf(t[c][r + i * 8]);
}

// ---------------- LayerNorm: 4 waves/block, one wave per row of 512 ----------------
__global__ __launch_bounds__(256) void ln_kernel(
    const float* __restrict__ x, const float* __restrict__ g,
    const float* __restrict__ be, float* __restrict__ outf,
    short* __restrict__ outb)
{
  int row = blockIdx.x * 4 + (threadIdx.x >> 6);
  int tid = threadIdx.x & 63;
  const float* xr = x + (size_t)row * D;
  float v[8];
  float sum = 0.f;
#pragma unroll
  for (int i = 0; i < 8; ++i) { v[i] = xr[tid + i * 64]; sum += v[i]; }
#pragma unroll
  for (int off = 32; off > 0; off >>= 1) sum += __shfl_down(sum, off);
  sum = __shfl(sum, 0);
  float mean = sum * (1.0f / D);
  float vs = 0.f;
#pragma unroll
  for (int i = 0; i < 8; ++i) { float d = v[i] - mean; vs += d * d; }
#pragma unroll
  for (int off = 32; off > 0; off >>= 1) vs += __shfl_down(vs, off);
  vs = __shfl(vs, 0);
  float rstd = rsqrtf(vs * (1.0f / D) + 1e-5f);
#pragma unroll
  for (int i = 0; i < 8; ++i) {
    int c = tid + i * 64;
    float o = (v[i] - mean) * rstd * g[c] + be[c];
    if (outb) outb[(size_t)row * D + c] = f2bf(o);
    else      outf[(size_t)row * D + c] = o;
  }
}

// ---------------- 128x128 bf16 MFMA GEMM, 4-stage LDS ring, raw barriers ----------
// RESUBMIT of round-2 design (bench container failed; code audit found no
// divergent barrier, no LDS overwrite hazard, no OOB).
// Block = 128x128 C-tile, 4 waves in 2x2; each wave owns a 64x64 quadrant
// (2x2 tiles of mfma_f32_32x32x16_bf16). BK=32. 4-stage LDS ring (64 KB),
// prefetch depth 3; counted s_waitcnt vmcnt(N) + raw s_barrier (NO __syncthreads,
// so prefetch loads stay in flight across barriers - intra-block pipelining that
// works at 1-2 blocks/CU).
// Bank-conflict fix (rule #21: both-sides-or-neither with global_load_lds):
// LDS slot q of row r holds global 16B-granule q ^ ((r>>1)&3); the staging
// SOURCE address applies the same XOR, LDS dest stays linear; ds_read applies
// the XOR on its granule. 16-way -> 4-way conflicts.
// Safety argument for the 2-barrier protocol: stage (c+3)&3 re-issued at iter c
// was last READ at iter c-1; each wave's ds_read results are consumed by MFMAs
// (compiler lgkmcnt waits) before its barrier-2, so after barrier-2 all reads
// completed -> overwrite safe. Barrier counts are wave-uniform (nch uniform).
// blockIdx.z = split-K slice (nkz). mode 0: Cb = bf16(acc);
// mode 1: Cf += acc (+bvec, kz==0 only) via atomicAdd when nkz>1;
// mode 2: Cb = bf16(gelu(acc+bvec)).
__global__ __launch_bounds__(256, 2) void gemm128_kernel(
    const short* __restrict__ A, const short* __restrict__ Bt,
    const float* __restrict__ bvec, float* __restrict__ Cf,
    short* __restrict__ Cb, int K, int Nc, int mode, int nkz)
{
  __shared__ __align__(16) short As[4][4096];   // stage s: 128 rows x 32 k
  __shared__ __align__(16) short Bs[4][4096];
  const int bm = blockIdx.y * 128, bn = blockIdx.x * 128;
  const int kz = blockIdx.z;
  const int t = threadIdx.x, wave = t >> 6, lane = t & 63;
  const int wr = wave >> 1, wc = wave & 1;
  const int l32 = lane & 31, half = lane >> 5;
  const int Kz = K / nkz;
  const int kw0 = kz * Kz;
  const int nch = Kz >> 5;          // K-steps of 32 (>= 8 for all our calls)

  // staging: wave w covers rows [w*32, w*32+32): instr i -> rows w*32+i*16+(lane>>2).
  // source granule XOR-swizzled by ((row>>1)&3) == ((lane>>3)&3) (row base == 0 mod 8).
  const int srow = lane >> 2;
  const int sseg = (lane & 3) ^ ((lane >> 3) & 3);
  const short* Ab = A  + (size_t)(bm + wave * 32 + srow) * K + kw0 + sseg * 8;
  const short* Bb = Bt + (size_t)(bn + wave * 32 + srow) * K + kw0 + sseg * 8;

  auto issue = [&](int s, int kc) {
    char* ab = (char*)As + s * 8192 + wave * 2048;
    char* bb = (char*)Bs + s * 8192 + wave * 2048;
#pragma unroll
    for (int i = 0; i < 2; ++i)
      __builtin_amdgcn_global_load_lds(
          (const __attribute__((address_space(1))) void*)(Ab + (size_t)i * 16 * K + kc),
          (__attribute__((address_space(3))) void*)(ab + i * 1024), 16, 0, 0);
#pragma unroll
    for (int i = 0; i < 2; ++i)
      __builtin_amdgcn_global_load_lds(
          (const __attribute__((address_space(1))) void*)(Bb + (size_t)i * 16 * K + kc),
          (__attribute__((address_space(3))) void*)(bb + i * 1024), 16, 0, 0);
  };

  // precomputed swizzled ds_read offsets (in shorts), loop-invariant
  const int key = (l32 >> 1) & 3;
  int offA0[2], offA1[2], offB0[2], offB1[2];
#pragma unroll
  for (int ks = 0; ks < 2; ++ks) {
    const int slot = ((ks * 2 + half) ^ key) * 8;
    offA0[ks] = (wr * 64 + l32) * 32 + slot;
    offA1[ks] = (wr * 64 + 32 + l32) * 32 + slot;
    offB0[ks] = (wc * 64 + l32) * 32 + slot;
    offB1[ks] = (wc * 64 + 32 + l32) * 32 + slot;
  }

  f32x16 acc[2][2];
#pragma unroll
  for (int i = 0; i < 2; ++i)
#pragma unroll
    for (int j = 0; j < 2; ++j)
#pragma unroll
      for (int r = 0; r < 16; ++r) acc[i][j][r] = 0.f;

  // prologue: fill 3 stages
#pragma unroll
  for (int c = 0; c < 3; ++c) if (c < nch) issue(c, c * 32);

  for (int c = 0; c < nch; ++c) {
    const int s = c & 3;
    if (c + 3 < nch) issue((c + 3) & 3, (c + 3) * 32);
    const int rem = nch - 1 - c;   // stages younger than stage s still in flight
    if (rem >= 3)      asm volatile("s_waitcnt vmcnt(12)" ::: "memory");
    else if (rem == 2) asm volatile("s_waitcnt vmcnt(8)" ::: "memory");
    else if (rem == 1) asm volatile("s_waitcnt vmcnt(4)" ::: "memory");
    else               asm volatile("s_waitcnt vmcnt(0)" ::: "memory");
    asm volatile("s_barrier" ::: "memory");   // stage s fully resident (all waves)

    const short* Ap = (const short*)((const char*)As + s * 8192);
    const short* Bp = (const short*)((const char*)Bs + s * 8192);
#pragma unroll
    for (int ks = 0; ks < 2; ++ks) {
      bf16x8 a0 = *(const bf16x8*)&Ap[offA0[ks]];
      bf16x8 a1 = *(const bf16x8*)&Ap[offA1[ks]];
      bf16x8 b0 = *(const bf16x8*)&Bp[offB0[ks]];
      bf16x8 b1 = *(const bf16x8*)&Bp[offB1[ks]];
      acc[0][0] = __builtin_amdgcn_mfma_f32_32x32x16_bf16(a0, b0, acc[0][0], 0, 0, 0);
      acc[0][1] = __builtin_amdgcn_mfma_f32_32x32x16_bf16(a0, b1, acc[0][1], 0, 0, 0);
      acc[1][0] = __builtin_amdgcn_mfma_f32_32x32x16_bf16(a1, b0, acc[1][0], 0, 0, 0);
      acc[1][1] = __builtin_amdgcn_mfma_f32_32x32x16_bf16(a1, b1, acc[1][1], 0, 0, 0);
    }
    asm volatile("s_barrier" ::: "memory");   // all waves done reading stage s
  }

  // ---- epilogue: each wave writes its own 64x64 quadrant ----
  float bv0 = 0.f, bv1 = 0.f;
  if (mode == 2 || (mode == 1 && kz == 0)) {
    bv0 = bvec[bn + wc * 64 + l32];
    bv1 = bvec[bn + wc * 64 + 32 + l32];
  }
#pragma unroll
  for (int ti = 0; ti < 2; ++ti)
#pragma unroll
    for (int tj = 0; tj < 2; ++tj) {
      const float vb = tj ? bv1 : bv0;
#pragma unroll
      for (int r = 0; r < 16; ++r) {
        const int row = bm + wr * 64 + ti * 32 + (r & 3) + 8 * (r >> 2) + 4 * half;
        const int col = bn + wc * 64 + tj * 32 + l32;
        const size_t idx = (size_t)row * Nc + col;
        const float v = acc[ti][tj][r];
        if (mode == 0) {
          Cb[idx] = f2bf(v);
        } else if (mode == 1) {
          if (nkz == 1) Cf[idx] += v + vb;
          else          atomicAdd(&Cf[idx], v + vb);
        } else {
          Cb[idx] = f2bf(gelu_f(v + vb));
        }
      }
    }
}

// ---------------- MFMA flash attention v2: S^T orientation, 1 barrier/ktile ----------------
__global__ __launch_bounds__(256) void attn_mfma_kernel(
    const short* __restrict__ qkv, const float* __restrict__ bias,
    short* __restrict__ o)
{
  constexpr int LDR = 72;
  __shared__ __align__(16) short Qs[64 * LDR];
  __shared__ __align__(16) short Ks[2][64 * LDR];
  __shared__ __align__(16) short Vt[2][64 * LDR];
  __shared__ __align__(16) short Ps[4 * 16 * LDR];

  const int q0 = blockIdx.x * 64;
  const int hh = blockIdx.y;
  const int b  = blockIdx.z;
  const int t  = threadIdx.x;
  const int wave = t >> 6;
  const int lane = t & 63;
  const int quad = lane >> 4;
  const int ln16 = lane & 15;
  const int srow = t >> 2, sseg = t & 3;

  {
    const short* qb = qkv + (size_t)(b * N + q0 + srow) * QKVS + hh * 64 + sseg * 16;
    *(bf16x8*)&Qs[srow * LDR + sseg * 16] = *(const bf16x8*)qb;
    *(bf16x8*)&Qs[srow * LDR + sseg * 16 + 8] = *(const bf16x8*)(qb + 8);
  }
  __syncthreads();

  const int qrow = wave * 16 + ln16;
  const bf16x8 qf0 = *(const bf16x8*)&Qs[qrow * LDR + quad * 8];
  const bf16x8 qf1 = *(const bf16x8*)&Qs[qrow * LDR + 32 + quad * 8];

  float m_run = -1e30f, l_run = 0.f;
  f32x4 Oacc[4];
#pragma unroll
  for (int dt = 0; dt < 4; ++dt) Oacc[dt] = (f32x4){0.f, 0.f, 0.f, 0.f};

  short* Psw = Ps + wave * 16 * LDR;
  const float* brow = bias + (size_t)(b * N + q0 + wave * 16 + ln16) * N;
  const short* kb0 = qkv + (size_t)b * N * QKVS + 512 + hh * 64 + sseg * 16;
  const short* vb0 = qkv + (size_t)b * N * QKVS + 1024 + hh * 64 + sseg * 16;

  bf16x8 k0r = *(const bf16x8*)(kb0 + (size_t)srow * QKVS);
  bf16x8 k1r = *(const bf16x8*)(kb0 + (size_t)srow * QKVS + 8);
  bf16x8 v0r = *(const bf16x8*)(vb0 + (size_t)srow * QKVS);
  bf16x8 v1r = *(const bf16x8*)(vb0 + (size_t)srow * QKVS + 8);
  float4 b4[4];
#pragma unroll
  for (int ks = 0; ks < 4; ++ks)
    b4[ks] = *(const float4*)&brow[ks * 16 + quad * 4];

  for (int kt = 0; kt < 16; ++kt) {
    const int p = kt & 1;
    *(bf16x8*)&Ks[p][srow * LDR + sseg * 16] = k0r;
    *(bf16x8*)&Ks[p][srow * LDR + sseg * 16 + 8] = k1r;
#pragma unroll
    for (int e = 0; e < 8; ++e) {
      Vt[p][(sseg * 16 + e) * LDR + srow] = v0r[e];
      Vt[p][(sseg * 16 + 8 + e) * LDR + srow] = v1r[e];
    }
    const int k0n = (kt + 1 < 16) ? (kt + 1) * 64 : 0;
    bf16x8 nk0 = *(const bf16x8*)(kb0 + (size_t)(k0n + srow) * QKVS);
    bf16x8 nk1 = *(const bf16x8*)(kb0 + (size_t)(k0n + srow) * QKVS + 8);
    bf16x8 nv0 = *(const bf16x8*)(vb0 + (size_t)(k0n + srow) * QKVS);
    bf16x8 nv1 = *(const bf16x8*)(vb0 + (size_t)(k0n + srow) * QKVS + 8);
    float4 bcur[4] = {b4[0], b4[1], b4[2], b4[3]};
#pragma unroll
    for (int ks = 0; ks < 4; ++ks)
      b4[ks] = *(const float4*)&brow[k0n + ks * 16 + quad * 4];
    asm volatile("s_waitcnt lgkmcnt(0)\n\ts_barrier" ::: "memory");

    float sv[4][4];
#pragma unroll
    for (int ks = 0; ks < 4; ++ks) {
      bf16x8 a0 = *(const bf16x8*)&Ks[p][(ks * 16 + ln16) * LDR + quad * 8];
      bf16x8 a1 = *(const bf16x8*)&Ks[p][(ks * 16 + ln16) * LDR + 32 + quad * 8];
      f32x4 z = (f32x4){0.f, 0.f, 0.f, 0.f};
      z = __builtin_amdgcn_mfma_f32_16x16x32_bf16(a0, qf0, z, 0, 0, 0);
      z = __builtin_amdgcn_mfma_f32_16x16x32_bf16(a1, qf1, z, 0, 0, 0);
#pragma unroll
      for (int r = 0; r < 4; ++r)
        sv[ks][r] = z[r] * 0.125f + (&bcur[ks].x)[r];
    }

    float mt = sv[0][0];
#pragma unroll
    for (int ks = 0; ks < 4; ++ks)
#pragma unroll
      for (int r = 0; r < 4; ++r) mt = fmaxf(mt, sv[ks][r]);
    mt = fmaxf(mt, __shfl_xor(mt, 16));
    mt = fmaxf(mt, __shfl_xor(mt, 32));
    const float m_new = fmaxf(m_run, mt);
    const float alpha = __expf(m_run - m_new);
    m_run = m_new;
    float rs = 0.f;
    float pv[4][4];
#pragma unroll
    for (int ks = 0; ks < 4; ++ks)
#pragma unroll
      for (int r = 0; r < 4; ++r) {
        float e = __expf(sv[ks][r] - m_new);
        pv[ks][r] = e;
        rs += e;
      }
    rs += __shfl_xor(rs, 16);
    rs += __shfl_xor(rs, 32);
    l_run = l_run * alpha + rs;
    float af[4];
#pragma unroll
    for (int r = 0; r < 4; ++r) af[r] = __shfl(alpha, quad * 4 + r);
#pragma unroll
    for (int dt = 0; dt < 4; ++dt)
#pragma unroll
      for (int r = 0; r < 4; ++r) Oacc[dt][r] *= af[r];

#pragma unroll
    for (int ks = 0; ks < 4; ++ks) {
      short4 pk = {f2bf(pv[ks][0]), f2bf(pv[ks][1]), f2bf(pv[ks][2]), f2bf(pv[ks][3])};
      *(short4*)&Psw[ln16 * LDR + ks * 16 + quad * 4] = pk;
    }

    bf16x8 ap0 = *(const bf16x8*)&Psw[ln16 * LDR + quad * 8];
    bf16x8 ap1 = *(const bf16x8*)&Psw[ln16 * LDR + 32 + quad * 8];
#pragma unroll
    for (int dt = 0; dt < 4; ++dt) {
      bf16x8 bv0 = *(const bf16x8*)&Vt[p][(dt * 16 + ln16) * LDR + quad * 8];
      bf16x8 bv1 = *(const bf16x8*)&Vt[p][(dt * 16 + ln16) * LDR + 32 + quad * 8];
      Oacc[dt] = __builtin_amdgcn_mfma_f32_16x16x32_bf16(ap0, bv0, Oacc[dt], 0, 0, 0);
      Oacc[dt] = __builtin_amdgcn_mfma_f32_16x16x32_bf16(ap1, bv1, Oacc[dt], 0, 0, 0);
    }

    k0r = nk0; k1r = nk1; v0r = nv0; v1r = nv1;
  }

  const float linv = 1.0f / l_run;
  float iv[4];
#pragma unroll
  for (int r = 0; r < 4; ++r) iv[r] = __shfl(linv, quad * 4 + r);
#pragma unroll
  for (int dt = 0; dt < 4; ++dt) {
#pragma unroll
    for (int r = 0; r < 4; ++r) {
      int row = q0 + wave * 16 + quad * 4 + r;
      o[(size_t)(b * N + row) * D + hh * 64 + dt * 16 + ln16] =
          f2bf(Oacc[dt][r] * iv[r]);
    }
  }
}

}  // namespace

extern "C" void kernel_launch(void* const* d_in, const int* in_sizes, int n_in,
                              void* d_out, int out_size, void* d_ws, size_t ws_size,
                              hipStream_t stream)
{
  const float* tokens  = (const float*)d_in[0];
  const float* xy      = (const float*)d_in[1];
  const float* Wq      = (const float*)d_in[2];
  const float* Wk      = (const float*)d_in[3];
  const float* Wv      = (const float*)d_in[4];
  const float* Wo      = (const float*)d_in[5];
  const float* bo      = (const float*)d_in[6];
  const float* W1      = (const float*)d_in[7];
  const float* b1      = (const float*)d_in[8];
  const float* W2      = (const float*)d_in[9];
  const float* b2      = (const float*)d_in[10];
  const float* g1      = (const float*)d_in[11];
  const float* be1     = (const float*)d_in[12];
  const float* g2      = (const float*)d_in[13];
  const float* be2     = (const float*)d_in[14];
  const float* gf      = (const float*)d_in[15];
  const float* bf      = (const float*)d_in[16];
  const int*   alive   = (const int*)d_in[17];
  const int*   species = (const int*)d_in[18];

  char* p = (char*)d_ws;
  float* bias = (float*)p; p += (size_t)B * N * N * 4;       // 16.78 MB
  float* x    = (float*)p; p += (size_t)M * D * 4;           // 8.39 MB
  short* h    = (short*)p; p += (size_t)M * D * 2;           // 4.19 MB
  short* qkv  = (short*)p; p += (size_t)M * DFFd * 2;        // 16.78 MB (ff aliases qkv)
  short* ff   = qkv;
  short* Wqkvt = (short*)p; p += (size_t)L * QKVS * D * 2;   // 9.44 MB
  short* Wot   = (short*)p; p += (size_t)L * D * D * 2;      // 3.15 MB
  short* W1t   = (short*)p; p += (size_t)L * DFFd * D * 2;   // 12.58 MB
  short* W2t   = (short*)p; p += (size_t)L * D * DFFd * 2;   // 12.58 MB

  hipMemcpyAsync(x, tokens, sizeof(float) * (size_t)M * D,
                 hipMemcpyDeviceToDevice, stream);
  bias_kernel<<<dim3(N / 256, N, B), 256, 0, stream>>>(xy, alive, species, bias);

  wprep_kernel<<<dim3(16, 16, L), 256, 0, stream>>>(
      Wq, Wqkvt + (size_t)0 * D * D, D, D, (size_t)D * D, (size_t)QKVS * D);
  wprep_kernel<<<dim3(16, 16, L), 256, 0, stream>>>(
      Wk, Wqkvt + (size_t)1 * D * D, D, D, (size_t)D * D, (size_t)QKVS * D);
  wprep_kernel<<<dim3(16, 16, L), 256, 0, stream>>>(
      Wv, Wqkvt + (size_t)2 * D * D, D, D, (size_t)D * D, (size_t)QKVS * D);
  wprep_kernel<<<dim3(16, 16, L), 256, 0, stream>>>(
      Wo, Wot, D, D, (size_t)D * D, (size_t)D * D);
  wprep_kernel<<<dim3(16, 64, L), 256, 0, stream>>>(
      W1, W1t, D, DFFd, (size_t)D * DFFd, (size_t)DFFd * D);
  wprep_kernel<<<dim3(64, 16, L), 256, 0, stream>>>(
      W2, W2t, DFFd, D, (size_t)DFFd * D, (size_t)D * DFFd);

  for (int l = 0; l < L; ++l) {
    ln_kernel<<<M / 4, 256, 0, stream>>>(x, g1 + l * D, be1 + l * D, nullptr, h);
    // QKV: M=4096 x N=1536 x K=512
    gemm128_kernel<<<dim3(QKVS / 128, M / 128, 1), 256, 0, stream>>>(
        h, Wqkvt + (size_t)l * QKVS * D, nullptr, nullptr, qkv, D, QKVS, 0, 1);
    attn_mfma_kernel<<<dim3(N / 64, H, B), 256, 0, stream>>>(qkv, bias, h);
    // Wo: 4096 x 512 x 512, split-K=2 -> 256 blocks, atomic residual add
    gemm128_kernel<<<dim3(D / 128, M / 128, 2), 256, 0, stream>>>(
        h, Wot + (size_t)l * D * D, bo + l * D, x, nullptr, D, D, 1, 2);
    ln_kernel<<<M / 4, 256, 0, stream>>>(x, g2 + l * D, be2 + l * D, nullptr, h);
    // W1: 4096 x 2048 x 512, gelu epilogue
    gemm128_kernel<<<dim3(DFFd / 128, M / 128, 1), 256, 0, stream>>>(
        h, W1t + (size_t)l * DFFd * D, b1 + l * DFFd, nullptr, ff, D, DFFd, 2, 1);
    // W2: 4096 x 512 x 2048, split-K=2 -> 256 blocks, atomic residual add
    gemm128_kernel<<<dim3(D / 128, M / 128, 2), 256, 0, stream>>>(
        ff, W2t + (size_t)l * D * DFFd, b2 + l * D, x, nullptr, DFFd, D, 1, 2);
  }
  ln_kernel<<<M / 4, 256, 0, stream>>>(x, gf, bf, (float*)d_out, nullptr);
}

// Round 4
// 1140.911 us; speedup vs baseline: 1.0716x; 1.0141x over previous
//
#include <hip/hip_runtime.h>
#include <math.h>

namespace {

constexpr int B = 4, N = 1024, D = 512, H = 8, DHd = 64, L = 6, DFFd = 2048;
constexpr int M = B * N;           // 4096
constexpr int QKVS = 3 * D;        // 1536, qkv row stride
constexpr float NEG = -1000000000.0f;
constexpr float R2c = 100.0f;

typedef __attribute__((ext_vector_type(8))) short bf16x8;
typedef __attribute__((ext_vector_type(4))) float f32x4;
typedef __attribute__((ext_vector_type(16))) float f32x16;

__device__ __forceinline__ short f2bf(float f) {
  union { float f; unsigned u; } c; c.f = f;
  unsigned r = (c.u + 0x7fffu + ((c.u >> 16) & 1u)) >> 16;
  return (short)r;
}

__device__ __forceinline__ float gelu_f(float x) {
  return 0.5f * x * (1.0f + erff(x * 0.70710678118654752f));
}

// ---------------- bias: (B,N,N) additive mask ----------------
__global__ __launch_bounds__(256) void bias_kernel(
    const float* __restrict__ xy, const int* __restrict__ alive,
    const int* __restrict__ species, float* __restrict__ bias)
{
  int j = blockIdx.x * 256 + threadIdx.x;
  int i = blockIdx.y;
  int b = blockIdx.z;
  float xi = xy[((size_t)b * N + i) * 2 + 0];
  float yi = xy[((size_t)b * N + i) * 2 + 1];
  float xj = xy[((size_t)b * N + j) * 2 + 0];
  float yj = xy[((size_t)b * N + j) * 2 + 1];
  float dx = xi - xj, dy = yi - yj;
  float d2 = dx * dx + dy * dy;
  float bv = 0.0f;
  if (alive[b * N + j] == 0) bv += NEG;
  if (d2 > R2c) bv += NEG;
  int si = species[b * N + i], sj = species[b * N + j];
  bool ia = si < 2, ip = si == 2, ja = sj < 2, jp = sj == 2;
  if ((ia && jp) || (ip && ja)) bv += NEG;
  bias[((size_t)b * N + i) * N + j] = bv;
}

// ---------------- weight prep: fp32 (K x Nc) -> bf16 transposed (Nc x K) ----------------
__global__ __launch_bounds__(256) void wprep_kernel(
    const float* __restrict__ src, short* __restrict__ dst,
    int K, int Nc, size_t srcLS, size_t dstLS)
{
  __shared__ float t[32][33];
  int k0 = blockIdx.x * 32, n0 = blockIdx.y * 32;
  src += (size_t)blockIdx.z * srcLS;
  dst += (size_t)blockIdx.z * dstLS;
  int r = threadIdx.x >> 5, c = threadIdx.x & 31;  // r: 0..7
#pragma unroll
  for (int i = 0; i < 4; ++i)
    t[r + i * 8][c] = src[(size_t)(k0 + r + i * 8) * Nc + n0 + c];
  __syncthreads();
#pragma unroll
  for (int i = 0; i < 4; ++i)
    dst[(size_t)(n0 + r + i * 8) * K + k0 + c] = f2bf(t[c][r + i * 8]);
}

// ---------------- LayerNorm: 4 waves/block, one wave per row of 512 ----------------
__global__ __launch_bounds__(256) void ln_kernel(
    const float* __restrict__ x, const float* __restrict__ g,
    const float* __restrict__ be, float* __restrict__ outf,
    short* __restrict__ outb)
{
  int row = blockIdx.x * 4 + (threadIdx.x >> 6);
  int tid = threadIdx.x & 63;
  const float* xr = x + (size_t)row * D;
  float v[8];
  float sum = 0.f;
#pragma unroll
  for (int i = 0; i < 8; ++i) { v[i] = xr[tid + i * 64]; sum += v[i]; }
#pragma unroll
  for (int off = 32; off > 0; off >>= 1) sum += __shfl_down(sum, off);
  sum = __shfl(sum, 0);
  float mean = sum * (1.0f / D);
  float vs = 0.f;
#pragma unroll
  for (int i = 0; i < 8; ++i) { float d = v[i] - mean; vs += d * d; }
#pragma unroll
  for (int off = 32; off > 0; off >>= 1) vs += __shfl_down(vs, off);
  vs = __shfl(vs, 0);
  float rstd = rsqrtf(vs * (1.0f / D) + 1e-5f);
#pragma unroll
  for (int i = 0; i < 8; ++i) {
    int c = tid + i * 64;
    float o = (v[i] - mean) * rstd * g[c] + be[c];
    if (outb) outb[(size_t)row * D + c] = f2bf(o);
    else      outf[(size_t)row * D + c] = o;
  }
}

// ---------------- 64x64-per-wave bf16 MFMA GEMM: barrier-free, TLP-latency-hiding ----
// One wave (64-thread block) owns one 64x64 C-tile over the full K (or K/nkz
// split-K slice). 2x2 tiles of mfma_f32_32x32x16_bf16, BK=32, wave-private
// double-buffered LDS (16 KB/block -> up to 10 blocks/CU; W1 grid = 2048 blocks
// = 8 resident waves/CU). NO barriers anywhere: each wave paces itself with
// s_waitcnt vmcnt(8) (next chunk's 8 global_load_lds stay in flight). Latency
// is hidden by 8 independent waves/CU (round-0's proven concurrency model),
// not by lock-step prefetch depth (rounds 1/3 showed that fails at 2 blocks/CU).
// Bank-conflict swizzle carried unchanged from round 3 (verified passing):
// LDS 16B-granule g of row r holds global granule g ^ ((r>>1)&3); staging
// SOURCE applies the XOR (sseg = (lane&3)^((lane>>3)&3)), LDS dest lds linear,
// ds_read applies the same XOR on its granule index.
// XCD-chunked bijective block swizzle (m204): each XCD gets a contiguous range
// of row-major tile space -> A-panels reused within one XCD's private L2.
// mode 0: Cb = bf16(acc); mode 1: Cf += acc (+bvec, kz==0 only) via atomicAdd
// when nkz>1; mode 2: Cb = bf16(gelu(acc+bvec)).
__global__ __launch_bounds__(64) void gemm64_kernel(
    const short* __restrict__ A, const short* __restrict__ Bt,
    const float* __restrict__ bvec, float* __restrict__ Cf,
    short* __restrict__ Cb, int K, int Nc, int mode, int nkz)
{
  __shared__ __align__(16) short sm[2][2][64 * 32];  // [buf][A=0/B=1][64 rows x 32 k]

  // bijective chunked XCD swizzle (m204): xcd = flat%8 gets contiguous chunk
  const int gx = gridDim.x;
  const int nwg = gx * gridDim.y;
  int flat = blockIdx.y * gx + blockIdx.x;
  {
    const int xcd = flat & 7, idx = flat >> 3;
    const int q = nwg >> 3, r = nwg & 7;
    flat = (xcd < r ? xcd * (q + 1) : r * (q + 1) + (xcd - r) * q) + idx;
  }
  const int bm = (flat / gx) * 64, bn = (flat % gx) * 64;
  const int kz = blockIdx.z;

  const int lane = threadIdx.x;
  const int l32 = lane & 31, half = lane >> 5;
  const int Kz = K / nkz;
  const int kw0 = kz * Kz;
  const int nch = Kz >> 5;          // chunks of BK=32 (>= 4 for all our calls)

  // staging: instr i covers rows i*16 + (lane>>2); lane fetches source granule
  // (lane&3)^((lane>>3)&3) of its row (inverse of the read-side XOR).
  const int srow = lane >> 2;
  const int sseg = (lane & 3) ^ ((lane >> 3) & 3);
  const short* Ab = A  + (size_t)(bm + srow) * K + kw0 + sseg * 8;
  const short* Bb = Bt + (size_t)(bn + srow) * K + kw0 + sseg * 8;

  auto issue = [&](int p, int kc) {
    char* ab = (char*)&sm[p][0][0];
    char* bb = (char*)&sm[p][1][0];
#pragma unroll
    for (int i = 0; i < 4; ++i)
      __builtin_amdgcn_global_load_lds(
          (const __attribute__((address_space(1))) void*)(Ab + (size_t)i * 16 * K + kc),
          (__attribute__((address_space(3))) void*)(ab + i * 1024), 16, 0, 0);
#pragma unroll
    for (int i = 0; i < 4; ++i)
      __builtin_amdgcn_global_load_lds(
          (const __attribute__((address_space(1))) void*)(Bb + (size_t)i * 16 * K + kc),
          (__attribute__((address_space(3))) void*)(bb + i * 1024), 16, 0, 0);
  };

  // swizzled ds_read offsets (shorts), loop-invariant
  const int key = (l32 >> 1) & 3;
  int offA0[2], offA1[2], offB0[2], offB1[2];
#pragma unroll
  for (int ks = 0; ks < 2; ++ks) {
    const int slot = ((ks * 2 + half) ^ key) * 8;
    offA0[ks] = l32 * 32 + slot;
    offA1[ks] = (32 + l32) * 32 + slot;
    offB0[ks] = l32 * 32 + slot;
    offB1[ks] = (32 + l32) * 32 + slot;
  }

  f32x16 acc[2][2];
#pragma unroll
  for (int i = 0; i < 2; ++i)
#pragma unroll
    for (int j = 0; j < 2; ++j)
#pragma unroll
      for (int r = 0; r < 16; ++r) acc[i][j][r] = 0.f;

  issue(0, 0);
  for (int c = 0; c < nch; ++c) {
    const int p = c & 1;
    if (c + 1 < nch) {
      issue(p ^ 1, (c + 1) * 32);
      asm volatile("s_waitcnt vmcnt(8)" ::: "memory");   // chunk c resident
    } else {
      asm volatile("s_waitcnt vmcnt(0)" ::: "memory");
    }
    const short* Ap = &sm[p][0][0];
    const short* Bp = &sm[p][1][0];
#pragma unroll
    for (int ks = 0; ks < 2; ++ks) {
      bf16x8 a0 = *(const bf16x8*)&Ap[offA0[ks]];
      bf16x8 a1 = *(const bf16x8*)&Ap[offA1[ks]];
      bf16x8 b0 = *(const bf16x8*)&Bp[offB0[ks]];
      bf16x8 b1 = *(const bf16x8*)&Bp[offB1[ks]];
      acc[0][0] = __builtin_amdgcn_mfma_f32_32x32x16_bf16(a0, b0, acc[0][0], 0, 0, 0);
      acc[0][1] = __builtin_amdgcn_mfma_f32_32x32x16_bf16(a0, b1, acc[0][1], 0, 0, 0);
      acc[1][0] = __builtin_amdgcn_mfma_f32_32x32x16_bf16(a1, b0, acc[1][0], 0, 0, 0);
      acc[1][1] = __builtin_amdgcn_mfma_f32_32x32x16_bf16(a1, b1, acc[1][1], 0, 0, 0);
    }
  }

  // ---- epilogue: direct global write of the wave's 64x64 tile ----
  float bv0 = 0.f, bv1 = 0.f;
  if (mode == 2 || (mode == 1 && kz == 0)) {
    bv0 = bvec[bn + l32];
    bv1 = bvec[bn + 32 + l32];
  }
#pragma unroll
  for (int ti = 0; ti < 2; ++ti)
#pragma unroll
    for (int tj = 0; tj < 2; ++tj) {
      const float vb = tj ? bv1 : bv0;
#pragma unroll
      for (int r = 0; r < 16; ++r) {
        const int row = bm + ti * 32 + (r & 3) + 8 * (r >> 2) + 4 * half;
        const int col = bn + tj * 32 + l32;
        const size_t idx = (size_t)row * Nc + col;
        const float v = acc[ti][tj][r];
        if (mode == 0) {
          Cb[idx] = f2bf(v);
        } else if (mode == 1) {
          if (nkz == 1) Cf[idx] += v + vb;
          else          atomicAdd(&Cf[idx], v + vb);
        } else {
          Cb[idx] = f2bf(gelu_f(v + vb));
        }
      }
    }
}

// ---------------- MFMA flash attention v2: S^T orientation, 1 barrier/ktile ----------------
__global__ __launch_bounds__(256) void attn_mfma_kernel(
    const short* __restrict__ qkv, const float* __restrict__ bias,
    short* __restrict__ o)
{
  constexpr int LDR = 72;
  __shared__ __align__(16) short Qs[64 * LDR];
  __shared__ __align__(16) short Ks[2][64 * LDR];
  __shared__ __align__(16) short Vt[2][64 * LDR];
  __shared__ __align__(16) short Ps[4 * 16 * LDR];

  const int q0 = blockIdx.x * 64;
  const int hh = blockIdx.y;
  const int b  = blockIdx.z;
  const int t  = threadIdx.x;
  const int wave = t >> 6;
  const int lane = t & 63;
  const int quad = lane >> 4;
  const int ln16 = lane & 15;
  const int srow = t >> 2, sseg = t & 3;

  {
    const short* qb = qkv + (size_t)(b * N + q0 + srow) * QKVS + hh * 64 + sseg * 16;
    *(bf16x8*)&Qs[srow * LDR + sseg * 16] = *(const bf16x8*)qb;
    *(bf16x8*)&Qs[srow * LDR + sseg * 16 + 8] = *(const bf16x8*)(qb + 8);
  }
  __syncthreads();

  const int qrow = wave * 16 + ln16;
  const bf16x8 qf0 = *(const bf16x8*)&Qs[qrow * LDR + quad * 8];
  const bf16x8 qf1 = *(const bf16x8*)&Qs[qrow * LDR + 32 + quad * 8];

  float m_run = -1e30f, l_run = 0.f;
  f32x4 Oacc[4];
#pragma unroll
  for (int dt = 0; dt < 4; ++dt) Oacc[dt] = (f32x4){0.f, 0.f, 0.f, 0.f};

  short* Psw = Ps + wave * 16 * LDR;
  const float* brow = bias + (size_t)(b * N + q0 + wave * 16 + ln16) * N;
  const short* kb0 = qkv + (size_t)b * N * QKVS + 512 + hh * 64 + sseg * 16;
  const short* vb0 = qkv + (size_t)b * N * QKVS + 1024 + hh * 64 + sseg * 16;

  bf16x8 k0r = *(const bf16x8*)(kb0 + (size_t)srow * QKVS);
  bf16x8 k1r = *(const bf16x8*)(kb0 + (size_t)srow * QKVS + 8);
  bf16x8 v0r = *(const bf16x8*)(vb0 + (size_t)srow * QKVS);
  bf16x8 v1r = *(const bf16x8*)(vb0 + (size_t)srow * QKVS + 8);
  float4 b4[4];
#pragma unroll
  for (int ks = 0; ks < 4; ++ks)
    b4[ks] = *(const float4*)&brow[ks * 16 + quad * 4];

  for (int kt = 0; kt < 16; ++kt) {
    const int p = kt & 1;
    *(bf16x8*)&Ks[p][srow * LDR + sseg * 16] = k0r;
    *(bf16x8*)&Ks[p][srow * LDR + sseg * 16 + 8] = k1r;
#pragma unroll
    for (int e = 0; e < 8; ++e) {
      Vt[p][(sseg * 16 + e) * LDR + srow] = v0r[e];
      Vt[p][(sseg * 16 + 8 + e) * LDR + srow] = v1r[e];
    }
    const int k0n = (kt + 1 < 16) ? (kt + 1) * 64 : 0;
    bf16x8 nk0 = *(const bf16x8*)(kb0 + (size_t)(k0n + srow) * QKVS);
    bf16x8 nk1 = *(const bf16x8*)(kb0 + (size_t)(k0n + srow) * QKVS + 8);
    bf16x8 nv0 = *(const bf16x8*)(vb0 + (size_t)(k0n + srow) * QKVS);
    bf16x8 nv1 = *(const bf16x8*)(vb0 + (size_t)(k0n + srow) * QKVS + 8);
    float4 bcur[4] = {b4[0], b4[1], b4[2], b4[3]};
#pragma unroll
    for (int ks = 0; ks < 4; ++ks)
      b4[ks] = *(const float4*)&brow[k0n + ks * 16 + quad * 4];
    asm volatile("s_waitcnt lgkmcnt(0)\n\ts_barrier" ::: "memory");

    float sv[4][4];
#pragma unroll
    for (int ks = 0; ks < 4; ++ks) {
      bf16x8 a0 = *(const bf16x8*)&Ks[p][(ks * 16 + ln16) * LDR + quad * 8];
      bf16x8 a1 = *(const bf16x8*)&Ks[p][(ks * 16 + ln16) * LDR + 32 + quad * 8];
      f32x4 z = (f32x4){0.f, 0.f, 0.f, 0.f};
      z = __builtin_amdgcn_mfma_f32_16x16x32_bf16(a0, qf0, z, 0, 0, 0);
      z = __builtin_amdgcn_mfma_f32_16x16x32_bf16(a1, qf1, z, 0, 0, 0);
#pragma unroll
      for (int r = 0; r < 4; ++r)
        sv[ks][r] = z[r] * 0.125f + (&bcur[ks].x)[r];
    }

    float mt = sv[0][0];
#pragma unroll
    for (int ks = 0; ks < 4; ++ks)
#pragma unroll
      for (int r = 0; r < 4; ++r) mt = fmaxf(mt, sv[ks][r]);
    mt = fmaxf(mt, __shfl_xor(mt, 16));
    mt = fmaxf(mt, __shfl_xor(mt, 32));
    const float m_new = fmaxf(m_run, mt);
    const float alpha = __expf(m_run - m_new);
    m_run = m_new;
    float rs = 0.f;
    float pv[4][4];
#pragma unroll
    for (int ks = 0; ks < 4; ++ks)
#pragma unroll
      for (int r = 0; r < 4; ++r) {
        float e = __expf(sv[ks][r] - m_new);
        pv[ks][r] = e;
        rs += e;
      }
    rs += __shfl_xor(rs, 16);
    rs += __shfl_xor(rs, 32);
    l_run = l_run * alpha + rs;
    float af[4];
#pragma unroll
    for (int r = 0; r < 4; ++r) af[r] = __shfl(alpha, quad * 4 + r);
#pragma unroll
    for (int dt = 0; dt < 4; ++dt)
#pragma unroll
      for (int r = 0; r < 4; ++r) Oacc[dt][r] *= af[r];

#pragma unroll
    for (int ks = 0; ks < 4; ++ks) {
      short4 pk = {f2bf(pv[ks][0]), f2bf(pv[ks][1]), f2bf(pv[ks][2]), f2bf(pv[ks][3])};
      *(short4*)&Psw[ln16 * LDR + ks * 16 + quad * 4] = pk;
    }

    bf16x8 ap0 = *(const bf16x8*)&Psw[ln16 * LDR + quad * 8];
    bf16x8 ap1 = *(const bf16x8*)&Psw[ln16 * LDR + 32 + quad * 8];
#pragma unroll
    for (int dt = 0; dt < 4; ++dt) {
      bf16x8 bv0 = *(const bf16x8*)&Vt[p][(dt * 16 + ln16) * LDR + quad * 8];
      bf16x8 bv1 = *(const bf16x8*)&Vt[p][(dt * 16 + ln16) * LDR + 32 + quad * 8];
      Oacc[dt] = __builtin_amdgcn_mfma_f32_16x16x32_bf16(ap0, bv0, Oacc[dt], 0, 0, 0);
      Oacc[dt] = __builtin_amdgcn_mfma_f32_16x16x32_bf16(ap1, bv1, Oacc[dt], 0, 0, 0);
    }

    k0r = nk0; k1r = nk1; v0r = nv0; v1r = nv1;
  }

  const float linv = 1.0f / l_run;
  float iv[4];
#pragma unroll
  for (int r = 0; r < 4; ++r) iv[r] = __shfl(linv, quad * 4 + r);
#pragma unroll
  for (int dt = 0; dt < 4; ++dt) {
#pragma unroll
    for (int r = 0; r < 4; ++r) {
      int row = q0 + wave * 16 + quad * 4 + r;
      o[(size_t)(b * N + row) * D + hh * 64 + dt * 16 + ln16] =
          f2bf(Oacc[dt][r] * iv[r]);
    }
  }
}

}  // namespace

extern "C" void kernel_launch(void* const* d_in, const int* in_sizes, int n_in,
                              void* d_out, int out_size, void* d_ws, size_t ws_size,
                              hipStream_t stream)
{
  const float* tokens  = (const float*)d_in[0];
  const float* xy      = (const float*)d_in[1];
  const float* Wq      = (const float*)d_in[2];
  const float* Wk      = (const float*)d_in[3];
  const float* Wv      = (const float*)d_in[4];
  const float* Wo      = (const float*)d_in[5];
  const float* bo      = (const float*)d_in[6];
  const float* W1      = (const float*)d_in[7];
  const float* b1      = (const float*)d_in[8];
  const float* W2      = (const float*)d_in[9];
  const float* b2      = (const float*)d_in[10];
  const float* g1      = (const float*)d_in[11];
  const float* be1     = (const float*)d_in[12];
  const float* g2      = (const float*)d_in[13];
  const float* be2     = (const float*)d_in[14];
  const float* gf      = (const float*)d_in[15];
  const float* bf      = (const float*)d_in[16];
  const int*   alive   = (const int*)d_in[17];
  const int*   species = (const int*)d_in[18];

  char* p = (char*)d_ws;
  float* bias = (float*)p; p += (size_t)B * N * N * 4;       // 16.78 MB
  float* x    = (float*)p; p += (size_t)M * D * 4;           // 8.39 MB
  short* h    = (short*)p; p += (size_t)M * D * 2;           // 4.19 MB
  short* qkv  = (short*)p; p += (size_t)M * DFFd * 2;        // 16.78 MB (ff aliases qkv)
  short* ff   = qkv;
  short* Wqkvt = (short*)p; p += (size_t)L * QKVS * D * 2;   // 9.44 MB
  short* Wot   = (short*)p; p += (size_t)L * D * D * 2;      // 3.15 MB
  short* W1t   = (short*)p; p += (size_t)L * DFFd * D * 2;   // 12.58 MB
  short* W2t   = (short*)p; p += (size_t)L * D * DFFd * 2;   // 12.58 MB

  hipMemcpyAsync(x, tokens, sizeof(float) * (size_t)M * D,
                 hipMemcpyDeviceToDevice, stream);
  bias_kernel<<<dim3(N / 256, N, B), 256, 0, stream>>>(xy, alive, species, bias);

  wprep_kernel<<<dim3(16, 16, L), 256, 0, stream>>>(
      Wq, Wqkvt + (size_t)0 * D * D, D, D, (size_t)D * D, (size_t)QKVS * D);
  wprep_kernel<<<dim3(16, 16, L), 256, 0, stream>>>(
      Wk, Wqkvt + (size_t)1 * D * D, D, D, (size_t)D * D, (size_t)QKVS * D);
  wprep_kernel<<<dim3(16, 16, L), 256, 0, stream>>>(
      Wv, Wqkvt + (size_t)2 * D * D, D, D, (size_t)D * D, (size_t)QKVS * D);
  wprep_kernel<<<dim3(16, 16, L), 256, 0, stream>>>(
      Wo, Wot, D, D, (size_t)D * D, (size_t)D * D);
  wprep_kernel<<<dim3(16, 64, L), 256, 0, stream>>>(
      W1, W1t, D, DFFd, (size_t)D * DFFd, (size_t)DFFd * D);
  wprep_kernel<<<dim3(64, 16, L), 256, 0, stream>>>(
      W2, W2t, DFFd, D, (size_t)DFFd * D, (size_t)D * DFFd);

  for (int l = 0; l < L; ++l) {
    ln_kernel<<<M / 4, 256, 0, stream>>>(x, g1 + l * D, be1 + l * D, nullptr, h);
    // QKV: 4096 x 1536 x 512 -> 24x64 = 1536 wave-blocks
    gemm64_kernel<<<dim3(QKVS / 64, M / 64, 1), 64, 0, stream>>>(
        h, Wqkvt + (size_t)l * QKVS * D, nullptr, nullptr, qkv, D, QKVS, 0, 1);
    attn_mfma_kernel<<<dim3(N / 64, H, B), 256, 0, stream>>>(qkv, bias, h);
    // Wo: 4096 x 512 x 512, split-K=2 -> 1024 wave-blocks, atomic residual add
    gemm64_kernel<<<dim3(D / 64, M / 64, 2), 64, 0, stream>>>(
        h, Wot + (size_t)l * D * D, bo + l * D, x, nullptr, D, D, 1, 2);
    ln_kernel<<<M / 4, 256, 0, stream>>>(x, g2 + l * D, be2 + l * D, nullptr, h);
    // W1: 4096 x 2048 x 512, gelu epilogue -> 32x64 = 2048 wave-blocks
    gemm64_kernel<<<dim3(DFFd / 64, M / 64, 1), 64, 0, stream>>>(
        h, W1t + (size_t)l * DFFd * D, b1 + l * DFFd, nullptr, ff, D, DFFd, 2, 1);
    // W2: 4096 x 512 x 2048, split-K=2 -> 1024 wave-blocks, atomic residual add
    gemm64_kernel<<<dim3(D / 64, M / 64, 2), 64, 0, stream>>>(
        ff, W2t + (size_t)l * D * DFFd, b2 + l * D, x, nullptr, DFFd, D, 1, 2);
  }
  ln_kernel<<<M / 4, 256, 0, stream>>>(x, gf, bf, (float*)d_out, nullptr);
}